// Round 15
// baseline (1950.960 us; speedup 1.0000x reference)
//
#include <hip/hip_runtime.h>

typedef unsigned short u16;
typedef __attribute__((ext_vector_type(8))) short bh8;   // 8 x bf16 bits (4 VGPRs)
typedef __attribute__((ext_vector_type(4))) float f4;    // MFMA accumulator

__device__ __forceinline__ float bf2f(u16 u) {
  union { unsigned int i; float f; } x; x.i = ((unsigned int)u) << 16; return x.f;
}
__device__ __forceinline__ u16 f2bf(float f) {
  union { float f; unsigned int i; } x; x.f = f;
  unsigned int r = x.i + 0x7fffu + ((x.i >> 16) & 1u);
  return (u16)(r >> 16);
}
__device__ __forceinline__ f4 mfma16(bh8 a, bh8 b, f4 c) {
  return __builtin_amdgcn_mfma_f32_16x16x32_bf16(a, b, c, 0, 0, 0);
}
__device__ __forceinline__ void gload16(const void* g, void* l) {
  __builtin_amdgcn_global_load_lds(
      (const __attribute__((address_space(1))) void*)g,
      (__attribute__((address_space(3))) void*)l, 16, 0, 0);
}

// swizzled LDS read: dense row-major array, byte-in-row XOR'd by (row&7)<<4
__device__ __forceinline__ bh8 rd8(const u16* arr, int row, int col, int rowbytes) {
  return *(const bh8*)((const char*)arr + row * rowbytes + ((col * 2) ^ ((row & 7) << 4)));
}

// ---------------- merged weight transpose: 8 jobs in one launch ----------------
// fp32 [R][C] -> bf16 [C*rmul+roff][R]
struct WTJobs {
  const float* src[8];
  u16* dst[8];
  int R[8], C[8], rmul[8], roff[8], ntx[8], base[8];  // base ascending
};

__global__ __launch_bounds__(256)
void wtrans_all(WTJobs jobs) {
  __shared__ float tile[32][33];
  int bid = blockIdx.x;
  int ji = 0;
#pragma unroll
  for (int k = 1; k < 8; ++k) ji += (bid >= jobs.base[k]);
  int rel = bid - jobs.base[ji];
  int ntx = jobs.ntx[ji];
  int bx = rel % ntx, by = rel / ntx;
  const float* src = jobs.src[ji];
  u16* dst = jobs.dst[ji];
  int R = jobs.R[ji], C = jobs.C[ji], rmul = jobs.rmul[ji], roff = jobs.roff[ji];

  int tx = threadIdx.x & 31, ty = threadIdx.x >> 5;
  int c0 = bx * 32, r0 = by * 32;
#pragma unroll
  for (int yy = 0; yy < 32; yy += 8)
    tile[ty + yy][tx] = src[(size_t)(r0 + ty + yy) * C + c0 + tx];
  __syncthreads();
#pragma unroll
  for (int yy = 0; yy < 32; yy += 8)
    dst[(size_t)((c0 + ty + yy) * rmul + roff) * R + r0 + tx] = f2bf(tile[tx][ty + yy]);
}

// ---------------- RMSNorm over D=2048, fp32 in -> bf16 out ----------------
__global__ __launch_bounds__(256)
void rmsnorm_k(const float* __restrict__ x, const float* __restrict__ w,
               u16* __restrict__ out) {
  int row = blockIdx.x, t = threadIdx.x;
  const float* xr = x + (size_t)row * 2048;
  float4 a = ((const float4*)xr)[t * 2];
  float4 b = ((const float4*)xr)[t * 2 + 1];
  float ss = a.x*a.x + a.y*a.y + a.z*a.z + a.w*a.w
           + b.x*b.x + b.y*b.y + b.z*b.z + b.w*b.w;
#pragma unroll
  for (int s = 32; s > 0; s >>= 1) ss += __shfl_xor(ss, s, 64);
  __shared__ float red[4];
  if ((t & 63) == 0) red[t >> 6] = ss;
  __syncthreads();
  float rr = rsqrtf((red[0] + red[1] + red[2] + red[3]) * (1.0f / 2048.0f) + 1e-6f);
  float v[8] = {a.x, a.y, a.z, a.w, b.x, b.y, b.z, b.w};
  int c0 = t * 8;
  u16* orow = out + (size_t)row * 2048 + c0;
#pragma unroll
  for (int j = 0; j < 8; ++j) orow[j] = f2bf(v[j] * rr * w[c0 + j]);
}

// ======================= gemm4: BK=64 one-barrier GEMM, BN=256 =======================
// BM=256, BN=256, BK=64, 8 waves (2 wm x 4 wn), wave tile 128x64, acc[8][4].
// 2 LDS slots of 64KB (A 32K + B 32K) = 128KB. Register-trimmed vs R12's
// spilling variant: ks=1 ds offsets = ks=0 ^ 64 (proof: (4+r_)^(row&7) =
// (r_^(row&7))^4 for r_<4); A/B stage bases for l>0 are base0 + l*64*K*2
// (wave-uniform -> SGPR). Peak regs ~212 < 256 cap -> no spill.
// Per K-step (slot S = kt&1; ladder correctness proven in R12/R14 gemm3):
//   STAGE(S^1, kt+1)  [8 gloads; slot S^1 fully read last step]
//   2 sub-phases ks=0,1: {12 ds_read (fb[4],fa[8]) -> lgkmcnt(0) ->
//     setprio(1) 32 MFMA setprio(0)}    [no inner barriers]
//   vmcnt(0) [kt+1 DMA had a full step of lead] ; ONE barrier.
// Halves per-CU sync events vs BK=32 (BM*BN*BK product 4.2M vs 2.1M).
// EPI 4: v panels / gate ; EPI 6: interleaved gate/up -> silu(gate)*up.
template <int EPI, typename OutT>
__global__ __launch_bounds__(512, 2)
void gemm4(const u16* __restrict__ A, const u16* __restrict__ Bt,
           OutT* __restrict__ C, void* __restrict__ aux, float scale,
           int M, int N, int K, int gx) {
  constexpr int SB = 65536;  // A 32KB + B 32KB
  __shared__ char lds[2 * SB];
  int t = threadIdx.x, lane = t & 63, w = t >> 6;
  int c_ = lane & 15, r_ = lane >> 4;
  int wm = w >> 2, wn = w & 3;

  int nwg = gridDim.x;
  int wg = (blockIdx.x & 7) * (nwg >> 3) + (blockIdx.x >> 3);
  int gy = nwg / gx;
  int bx = wg / gy, by = wg % gy;
  int m0 = by * 256, n0 = bx * 256;

  int trow = t >> 3;
  int kchunk = (t & 7) ^ (trow & 7);  // pre-swizzled global k-chunk
  const char* baseA = (const char*)A + ((size_t)(m0 + trow) * K + kchunk * 8) * 2;
  const char* baseB = (const char*)Bt + ((size_t)(n0 + trow) * K + kchunk * 8) * 2;
  size_t rowStride = (size_t)64 * K * 2;  // uniform -> SGPR

  int offA[8], offB[4];
#pragma unroll
  for (int mb = 0; mb < 8; ++mb) {
    int row = wm * 128 + mb * 16 + c_;
    offA[mb] = row * 128 + ((r_ ^ (row & 7)) << 4);
  }
#pragma unroll
  for (int nb = 0; nb < 4; ++nb) {
    int n = wn * 64 + nb * 16 + c_;
    offB[nb] = 32768 + n * 128 + ((r_ ^ (n & 7)) << 4);
  }
  int ldsW = w * 1024;

  f4 z4 = {0.f, 0.f, 0.f, 0.f};
  f4 acc[8][4];
#pragma unroll
  for (int mb = 0; mb < 8; ++mb)
#pragma unroll
    for (int nb = 0; nb < 4; ++nb) acc[mb][nb] = z4;

  int NT = K >> 6;  // K=2048 -> 32

#define STAGE(S, ko)                                                          \
  {                                                                           \
    _Pragma("unroll") for (int l = 0; l < 4; ++l)                             \
        gload16(baseA + l * rowStride + (ko), lds + (S) * SB + l * 8192 + ldsW); \
    _Pragma("unroll") for (int l = 0; l < 4; ++l)                             \
        gload16(baseB + l * rowStride + (ko),                                 \
                lds + (S) * SB + 32768 + l * 8192 + ldsW);                    \
  }
#define KT64(S)                                                               \
  {                                                                           \
    int kts = kt + 1; if (kts >= NT) kts -= NT;                               \
    STAGE((S) ^ 1, kts << 7);                                                 \
    _Pragma("unroll")                                                         \
    for (int ks = 0; ks < 2; ++ks) {                                          \
      const int kx = ks ? 64 : 0;                                             \
      bh8 fb[4], fa[8];                                                       \
      _Pragma("unroll") for (int nb = 0; nb < 4; ++nb)                        \
          fb[nb] = *(const bh8*)(lds + (S) * SB + (offB[nb] ^ kx));           \
      _Pragma("unroll") for (int mb = 0; mb < 8; ++mb)                        \
          fa[mb] = *(const bh8*)(lds + (S) * SB + (offA[mb] ^ kx));           \
      asm volatile("s_waitcnt lgkmcnt(0)" ::: "memory");                      \
      __builtin_amdgcn_sched_barrier(0);                                      \
      __builtin_amdgcn_s_setprio(1);                                          \
      _Pragma("unroll") for (int mb = 0; mb < 8; ++mb)                        \
          _Pragma("unroll") for (int nb = 0; nb < 4; ++nb)                    \
              acc[mb][nb] = mfma16(fa[mb], fb[nb], acc[mb][nb]);              \
      __builtin_amdgcn_s_setprio(0);                                          \
      __builtin_amdgcn_sched_barrier(0);                                      \
    }                                                                         \
    asm volatile("s_waitcnt vmcnt(0)" ::: "memory");                          \
    __builtin_amdgcn_s_barrier();                                             \
    asm volatile("" ::: "memory");                                            \
  }

  STAGE(0, 0);
  asm volatile("s_waitcnt vmcnt(0)" ::: "memory");
  __builtin_amdgcn_s_barrier();
  asm volatile("" ::: "memory");

  int kt = 0;
  while (true) {
    KT64(0); if (++kt == NT) break;
    KT64(1); if (++kt == NT) break;
  }
#undef KT64
#undef STAGE

  int rowBase = m0 + wm * 128;
#pragma unroll
  for (int mb = 0; mb < 8; ++mb) {
#pragma unroll
    for (int rr = 0; rr < 4; ++rr) {
      int row = rowBase + mb * 16 + r_ * 4 + rr;
#pragma unroll
      for (int nb = 0; nb < 4; ++nb) {
        int col = n0 + wn * 64 + nb * 16 + c_;
        float val = acc[mb][nb][rr];
        if (EPI == 4) {
          if (col < 2048) {
            int bb = row >> 11, t2 = row & 2047;
            int pan = ((bb << 5) + (t2 >> 6)) * 8 + (col >> 8);
            int ii = t2 & 63, vv = col & 255;
            *(u16*)((char*)C + (size_t)pan * 32768 + vv * 128 + ((ii * 2) ^ ((vv & 7) << 4)))
                = f2bf(val);
          } else {
            ((u16*)aux)[(size_t)row * 2048 + col - 2048] = f2bf(val);
          }
        } else if (EPI == 6) {
          float other = __shfl_xor(val, 1, 64);
          if (lane & 1) {
            float gv = other;
            ((u16*)C)[(size_t)row * 5504 + (col >> 1)] = f2bf(val * (gv / (1.f + expf(-gv))));
          }
        }
      }
    }
  }
}

// ======================= gemm3: BK=64 one-barrier GEMM, BN=128 =======================
// BM=256, BN=128, BK=64, 8 waves (4 wm x 2 wn), wave tile 64x64, acc[4][4].
// 2 LDS slots of 48KB. Proven R14 config.
// EPI 1: C fp32 = acc + auxF32 ; EPI 5: q/k split.
template <int EPI, typename OutT>
__global__ __launch_bounds__(512, 2)
void gemm3(const u16* __restrict__ A, const u16* __restrict__ Bt,
           OutT* __restrict__ C, void* __restrict__ aux, float scale,
           int M, int N, int K, int gx) {
  constexpr int SB = 49152;  // A 32KB + B 16KB
  __shared__ char lds[2 * SB];
  int t = threadIdx.x, lane = t & 63, w = t >> 6;
  int c_ = lane & 15, r_ = lane >> 4;
  int wm = w >> 1, wn = w & 1;

  int nwg = gridDim.x;
  int wg = (blockIdx.x & 7) * (nwg >> 3) + (blockIdx.x >> 3);
  int gy = nwg / gx;
  int bx = wg / gy, by = wg % gy;
  int m0 = by * 256, n0 = bx * 128;

  int trow = t >> 3;
  int kchunk = (t & 7) ^ (trow & 7);  // pre-swizzled global k-chunk
  const char* baseA[4];
#pragma unroll
  for (int l = 0; l < 4; ++l)
    baseA[l] = (const char*)A + ((size_t)(m0 + l * 64 + trow) * K + kchunk * 8) * 2;
  const char* baseB[2];
#pragma unroll
  for (int l = 0; l < 2; ++l)
    baseB[l] = (const char*)Bt + ((size_t)(n0 + l * 64 + trow) * K + kchunk * 8) * 2;

  int offA[4][2], offB[4][2];
#pragma unroll
  for (int mb = 0; mb < 4; ++mb) {
    int row = wm * 64 + mb * 16 + c_;
#pragma unroll
    for (int ks = 0; ks < 2; ++ks)
      offA[mb][ks] = row * 128 + (((ks * 4 + r_) ^ (row & 7)) << 4);
  }
#pragma unroll
  for (int nb = 0; nb < 4; ++nb) {
    int n = wn * 64 + nb * 16 + c_;
#pragma unroll
    for (int ks = 0; ks < 2; ++ks)
      offB[nb][ks] = 32768 + n * 128 + (((ks * 4 + r_) ^ (n & 7)) << 4);
  }
  int ldsW = w * 1024;

  f4 z4 = {0.f, 0.f, 0.f, 0.f};
  f4 acc[4][4];
#pragma unroll
  for (int mb = 0; mb < 4; ++mb)
#pragma unroll
    for (int nb = 0; nb < 4; ++nb) acc[mb][nb] = z4;

  int NT = K >> 6;  // K=2048 -> 32, K=5504 -> 86

#define STAGE(S, ko)                                                        \
  {                                                                         \
    _Pragma("unroll") for (int l = 0; l < 4; ++l)                           \
        gload16(baseA[l] + (ko), lds + (S) * SB + l * 8192 + ldsW);         \
    _Pragma("unroll") for (int l = 0; l < 2; ++l)                           \
        gload16(baseB[l] + (ko), lds + (S) * SB + 32768 + l * 8192 + ldsW); \
  }
#define KT64(S)                                                             \
  {                                                                         \
    int kts = kt + 1; if (kts >= NT) kts -= NT;                             \
    STAGE((S) ^ 1, kts << 7);                                               \
    _Pragma("unroll")                                                       \
    for (int ks = 0; ks < 2; ++ks) {                                        \
      bh8 fb[4], fa[4];                                                     \
      _Pragma("unroll") for (int nb = 0; nb < 4; ++nb)                      \
          fb[nb] = *(const bh8*)(lds + (S) * SB + offB[nb][ks]);            \
      _Pragma("unroll") for (int mb = 0; mb < 4; ++mb)                      \
          fa[mb] = *(const bh8*)(lds + (S) * SB + offA[mb][ks]);            \
      asm volatile("s_waitcnt lgkmcnt(0)" ::: "memory");                    \
      __builtin_amdgcn_sched_barrier(0);                                    \
      __builtin_amdgcn_s_setprio(1);                                        \
      _Pragma("unroll") for (int mb = 0; mb < 4; ++mb)                      \
          _Pragma("unroll") for (int nb = 0; nb < 4; ++nb)                  \
              acc[mb][nb] = mfma16(fa[mb], fb[nb], acc[mb][nb]);            \
      __builtin_amdgcn_s_setprio(0);                                        \
      __builtin_amdgcn_sched_barrier(0);                                    \
    }                                                                       \
    asm volatile("s_waitcnt vmcnt(0)" ::: "memory");                        \
    __builtin_amdgcn_s_barrier();                                           \
    asm volatile("" ::: "memory");                                          \
  }

  STAGE(0, 0);
  asm volatile("s_waitcnt vmcnt(0)" ::: "memory");
  __builtin_amdgcn_s_barrier();
  asm volatile("" ::: "memory");

  int kt = 0;
  while (true) {
    KT64(0); if (++kt == NT) break;
    KT64(1); if (++kt == NT) break;
  }
#undef KT64
#undef STAGE

  int rowBase = m0 + wm * 64;
#pragma unroll
  for (int mb = 0; mb < 4; ++mb) {
#pragma unroll
    for (int rr = 0; rr < 4; ++rr) {
      int row = rowBase + mb * 16 + r_ * 4 + rr;
#pragma unroll
      for (int nb = 0; nb < 4; ++nb) {
        int col = n0 + wn * 64 + nb * 16 + c_;
        float val = acc[mb][nb][rr];
        if (EPI == 1) {
          ((float*)C)[(size_t)row * N + col] = val + ((const float*)aux)[(size_t)row * N + col];
        } else if (EPI == 5) {
          if (col < 1024) ((u16*)C)[(size_t)row * 1024 + col] = f2bf(val * scale);
          else ((u16*)aux)[(size_t)row * 1024 + col - 1024] = f2bf(val);
        }
      }
    }
  }
}

// ---------------- low-rank gate path: g = log_sigmoid(h@w1@w2 + b)/16 ----------------
__global__ __launch_bounds__(256)
void lowrank_k(const u16* __restrict__ h, const float* __restrict__ w1,
               const float* __restrict__ w2, const float* __restrict__ bias,
               float* __restrict__ g) {
  int row = blockIdx.x, t = threadIdx.x, lane = t & 63, wave = t >> 6;
  const u16* hr = h + (size_t)row * 2048;
  bh8 hv = *(const bh8*)&hr[t * 8];
  float p[16];
#pragma unroll
  for (int j = 0; j < 16; ++j) p[j] = 0.f;
#pragma unroll
  for (int kk = 0; kk < 8; ++kk) {
    float f = bf2f((u16)hv[kk]);
    const float* wrow = w1 + (size_t)(t * 8 + kk) * 16;
#pragma unroll
    for (int j = 0; j < 16; ++j) p[j] += f * wrow[j];
  }
#pragma unroll
  for (int j = 0; j < 16; ++j)
#pragma unroll
    for (int s = 32; s > 0; s >>= 1) p[j] += __shfl_xor(p[j], s, 64);
  __shared__ float gl[4][16];
  if (lane == 0) {
#pragma unroll
    for (int j = 0; j < 16; ++j) gl[wave][j] = p[j];
  }
  __syncthreads();
  float glow[16];
#pragma unroll
  for (int j = 0; j < 16; ++j) glow[j] = gl[0][j] + gl[1][j] + gl[2][j] + gl[3][j];
  float* grow = g + (size_t)row * 1024;
#pragma unroll
  for (int nn = 0; nn < 4; ++nn) {
    int n = nn * 256 + t;
    float z = bias[n];
#pragma unroll
    for (int j = 0; j < 16; ++j) z += glow[j] * w2[j * 1024 + n];
    float ls = fminf(z, 0.f) - log1pf(expf(-fabsf(z)));
    grow[n] = ls * (1.0f / 16.0f);
  }
}

// ---------------- gating prep (parallel over B*nc*H = 512 blocks) ----------------
__global__ __launch_bounds__(128)
void gprep_k(u16* __restrict__ q, u16* __restrict__ k, const float* __restrict__ g,
             u16* __restrict__ keT, float* __restrict__ ebl) {
  int bid = blockIdx.x;            // ((b*32+c)*8+h)
  int h = bid & 7, bc = bid >> 3;
  int b = bc >> 5, c = bc & 31;
  int ch = threadIdx.x;            // 0..127
  size_t base = ((size_t)(b * 2048 + c * 64)) * 1024 + h * 128 + ch;
  char* keTp = (char*)keT + (size_t)bid * 16384 + ch * 128;
  int sw = (ch & 7) << 4;
  float bacc = 0.f;
  for (int i8 = 0; i8 < 8; ++i8) {
    u16 kp[8];
#pragma unroll
    for (int e = 0; e < 8; ++e) {
      size_t off = base + (size_t)(i8 * 8 + e) * 1024;
      bacc += g[off];
      float eb = __expf(bacc);
      float reb = __builtin_amdgcn_rcpf(eb);
      float qv = bf2f(q[off]), kv = bf2f(k[off]);
      q[off] = f2bf(qv * eb);
      u16 kev = f2bf(kv * reb);
      k[off] = kev;
      kp[e] = kev;
    }
    *(bh8*)(keTp + ((i8 * 16) ^ sw)) = *(const bh8*)kp;
  }
  ebl[(size_t)bid * 128 + ch] = __expf(bacc);
}

// ---------------- GLA chunked scan (inter + intra, MFMA only) ----------------
__global__ __launch_bounds__(256)
void gla_scan(const u16* __restrict__ qg, const u16* __restrict__ kg,
              const u16* __restrict__ keTg, const u16* __restrict__ vTg,
              const float* __restrict__ eblg, float* __restrict__ outp) {
  __shared__ u16 qeL[64 * 128];   // [i][ch] swizzled
  __shared__ u16 keL[64 * 128];   // [i][ch] swizzled
  __shared__ u16 kTL[128 * 64];   // [ch][i] swizzled (baked by gprep)
  __shared__ u16 vTL[64 * 64];    // [v][i]  swizzled (baked by V-GEMM)
  __shared__ u16 AL[64 * 64];     // [i][j]  swizzled
  __shared__ u16 SbL[64 * 128];   // S^T bf16 [v][ch] swizzled
  __shared__ float SfL[64][133];  // S^T fp32 master (padded)

  int t = threadIdx.x, lane = t & 63, w = t >> 6;
  int vb = blockIdx.x & 3, bh = blockIdx.x >> 2;
  int b = bh >> 3, h = bh & 7;
  int c_ = lane & 15, r_ = lane >> 4;
  f4 z4 = {0.f, 0.f, 0.f, 0.f};

  for (int i = t; i < 64 * 128; i += 256) SbL[i] = 0;
  for (int i = t; i < 64 * 133; i += 256) ((float*)SfL)[i] = 0.f;

  const char* qbase = (const char*)qg + (size_t)b * 2048 * 2048 + h * 256;
  const char* kbase = (const char*)kg + (size_t)b * 2048 * 2048 + h * 256;
  int rowoff = (t >> 4) * 2048 + (t & 15) * 16;
  int4 pq[4], pk[4], pkt[4], pvt[2];

#define LOADCH(cc)                                                              \
  {                                                                             \
    const char* qc = qbase + (size_t)(cc) * 64 * 2048;                          \
    const char* kc = kbase + (size_t)(cc) * 64 * 2048;                          \
    int panel_ = ((b * 32 + (cc)) * 8 + h);                                     \
    const char* ktc = (const char*)keTg + (size_t)panel_ * 16384;               \
    const char* vtc = (const char*)vTg + (size_t)panel_ * 32768 + vb * 8192;    \
    _Pragma("unroll")                                                           \
    for (int j = 0; j < 4; ++j) {                                               \
      pq[j] = *(const int4*)(qc + j * 16 * 2048 + rowoff);                      \
      pk[j] = *(const int4*)(kc + j * 16 * 2048 + rowoff);                      \
      pkt[j] = *(const int4*)(ktc + j * 4096 + t * 16);                         \
    }                                                                           \
    _Pragma("unroll")                                                           \
    for (int j = 0; j < 2; ++j) pvt[j] = *(const int4*)(vtc + j * 4096 + t * 16); \
  }

  LOADCH(0);
  for (int c = 0; c < 32; ++c) {
#pragma unroll
    for (int j = 0; j < 4; ++j) {
      int L = j * 4096 + t * 16;
      int d = (L & ~255) | ((L & 255) ^ (((L >> 8) & 7) << 4));
      *(int4*)((char*)qeL + d) = pq[j];
      *(int4*)((char*)keL + d) = pk[j];
      *(int4*)((char*)kTL + L) = pkt[j];
    }
#pragma unroll
    for (int j = 0; j < 2; ++j) *(int4*)((char*)vTL + j * 4096 + t * 16) = pvt[j];
    if (c < 31) LOADCH(c + 1);
    int panel = ((b * 32 + c) * 8 + h);
    float eblr[2][4];
#pragma unroll
    for (int kt = 0; kt < 2; ++kt)
#pragma unroll
      for (int r = 0; r < 4; ++r)
        eblr[kt][r] = eblg[(size_t)panel * 128 + w * 32 + kt * 16 + r_ * 4 + r];
    __syncthreads();

    // phase 2: A = tril(qe@ke^T)  and  accS = keT@v
    f4 accA[4] = {z4, z4, z4, z4};
    f4 accS[2][4] = {{z4, z4, z4, z4}, {z4, z4, z4, z4}};
#pragma unroll
    for (int ks = 0; ks < 4; ++ks) {
      bh8 a = rd8(qeL, w * 16 + c_, ks * 32 + r_ * 8, 256);
#pragma unroll
      for (int n = 0; n < 4; ++n)
        accA[n] = mfma16(a, rd8(keL, n * 16 + c_, ks * 32 + r_ * 8, 256), accA[n]);
    }
#pragma unroll
    for (int ks = 0; ks < 2; ++ks) {
      bh8 bf_[4];
#pragma unroll
      for (int n = 0; n < 4; ++n) bf_[n] = rd8(vTL, n * 16 + c_, ks * 32 + r_ * 8, 128);
#pragma unroll
      for (int kt = 0; kt < 2; ++kt) {
        bh8 a = rd8(kTL, w * 32 + kt * 16 + c_, ks * 32 + r_ * 8, 128);
#pragma unroll
        for (int n = 0; n < 4; ++n) accS[kt][n] = mfma16(a, bf_[n], accS[kt][n]);
      }
    }
#pragma unroll
    for (int n = 0; n < 4; ++n)
#pragma unroll
      for (int r = 0; r < 4; ++r) {
        int i = w * 16 + r_ * 4 + r, j = n * 16 + c_;
        *(u16*)((char*)AL + i * 128 + ((j * 2) ^ ((i & 7) << 4))) =
            (j <= i) ? f2bf(accA[n][r]) : (u16)0;
      }
    __syncthreads();

    // phase 3: o = qe@S^T' + A@v
    f4 acco[4] = {z4, z4, z4, z4};
#pragma unroll
    for (int ks = 0; ks < 4; ++ks) {
      bh8 a = rd8(qeL, w * 16 + c_, ks * 32 + r_ * 8, 256);
#pragma unroll
      for (int n = 0; n < 4; ++n)
        acco[n] = mfma16(a, rd8(SbL, n * 16 + c_, ks * 32 + r_ * 8, 256), acco[n]);
    }
#pragma unroll
    for (int ks = 0; ks < 2; ++ks) {
      bh8 a = rd8(AL, w * 16 + c_, ks * 32 + r_ * 8, 128);
#pragma unroll
      for (int n = 0; n < 4; ++n)
        acco[n] = mfma16(a, rd8(vTL, n * 16 + c_, ks * 32 + r_ * 8, 128), acco[n]);
    }
    {
      size_t obase = (size_t)(b * 2048 + c * 64 + w * 16 + r_ * 4) * 2048 + h * 256 + vb * 64;
#pragma unroll
      for (int n = 0; n < 4; ++n)
#pragma unroll
        for (int r = 0; r < 4; ++r)
          outp[obase + (size_t)r * 2048 + n * 16 + c_] = acco[n][r];
    }
    __syncthreads();

    // phase 4: S = ebl * (S + accS)
#pragma unroll
    for (int kt = 0; kt < 2; ++kt)
#pragma unroll
      for (int n = 0; n < 4; ++n)
#pragma unroll
        for (int r = 0; r < 4; ++r) {
          int kk = w * 32 + kt * 16 + r_ * 4 + r;
          int vcol = n * 16 + c_;
          float nv = eblr[kt][r] * (SfL[vcol][kk] + accS[kt][n][r]);
          SfL[vcol][kk] = nv;
          *(u16*)((char*)SbL + vcol * 256 + ((kk * 2) ^ ((vcol & 7) << 4))) = f2bf(nv);
        }
    __syncthreads();
  }
#undef LOADCH
}

// ---------------- per-head RMSNorm * swish(gate) ----------------
__global__ __launch_bounds__(256)
void ogate_k(const float* __restrict__ o, const u16* __restrict__ gate,
             const float* __restrict__ gw, u16* __restrict__ og) {
  int tok = blockIdx.x, t = threadIdx.x;
  int head = t >> 5, l32 = t & 31, v0 = l32 * 8;
  size_t base = (size_t)tok * 2048 + head * 256 + v0;
  float4 a = *(const float4*)&o[base];
  float4 b = *(const float4*)&o[base + 4];
  float ov[8] = {a.x, a.y, a.z, a.w, b.x, b.y, b.z, b.w};
  float ss = 0.f;
#pragma unroll
  for (int j = 0; j < 8; ++j) ss += ov[j] * ov[j];
#pragma unroll
  for (int s = 16; s > 0; s >>= 1) ss += __shfl_xor(ss, s, 32);
  float rr = rsqrtf(ss * (1.0f / 256.0f) + 1e-6f);
#pragma unroll
  for (int j = 0; j < 8; ++j) {
    float gv = bf2f(gate[base + j]);
    float val = ov[j] * rr * gw[v0 + j];
    og[base + j] = f2bf(val * gv / (1.f + expf(-gv)));
  }
}

// ---------------- launch ----------------
extern "C" void kernel_launch(void* const* d_in, const int* in_sizes, int n_in,
                              void* d_out, int out_size, void* d_ws, size_t ws_size,
                              hipStream_t stream) {
  (void)in_sizes; (void)n_in; (void)out_size; (void)ws_size;
  const float* x = (const float*)d_in[0];
  const float* n1w = (const float*)d_in[1];
  const float* wq = (const float*)d_in[2];
  const float* wk = (const float*)d_in[3];
  const float* wv = (const float*)d_in[4];
  const float* gw1 = (const float*)d_in[5];
  const float* gw2 = (const float*)d_in[6];
  const float* gb = (const float*)d_in[7];
  const float* wg = (const float*)d_in[8];
  const float* gnw = (const float*)d_in[9];
  const float* wo = (const float*)d_in[10];
  const float* fnw = (const float*)d_in[11];
  const float* wgate = (const float*)d_in[12];
  const float* wup = (const float*)d_in[13];
  const float* wdown = (const float*)d_in[14];
  float* out = (float*)d_out;

  char* ws = (char*)d_ws;
  size_t off = 0;
  auto alloc = [&](size_t bytes) { size_t p = off; off += (bytes + 255) & ~(size_t)255; return p; };
  u16* wqT = (u16*)(ws + alloc(2ull * 1024 * 2048));   // [contiguous with wkT -> qk Bt]
  u16* wkT = (u16*)(ws + alloc(2ull * 1024 * 2048));
  u16* wvT = (u16*)(ws + alloc(2ull * 2048 * 2048));   // [contiguous with wgT -> vg Bt]
  u16* wgT = (u16*)(ws + alloc(2ull * 2048 * 2048));
  u16* woT = (u16*)(ws + alloc(2ull * 2048 * 2048));
  u16* btGU = (u16*)(ws + alloc(2ull * 11008 * 2048)); // interleaved gate/up
  u16* wdT = (u16*)(ws + alloc(2ull * 2048 * 5504));
  u16* h_bf = (u16*)(ws + alloc(2ull * 4096 * 2048));  // h -> keT panels -> og
  u16* q_bf = (u16*)(ws + alloc(2ull * 4096 * 1024));  // q -> qe (in place) -> h2
  u16* k_bf = (u16*)(ws + alloc(2ull * 4096 * 1024));  // k -> ke (in place)
  u16* vT_g = (u16*)(ws + alloc(2ull * 4096 * 2048));  // v panels [512][256][64] swizzled
  u16* gate_bf = (u16*)(ws + alloc(2ull * 4096 * 2048));
  float* g_f = (float*)(ws + alloc(4ull * 4096 * 1024));
  float* o_f = (float*)(ws + alloc(4ull * 4096 * 2048));  // later reused as x2
  u16* mid = (u16*)(ws + alloc(2ull * 4096 * 5504));
  float* ebl_g = (float*)(ws + alloc(4ull * 512 * 128));
  u16* keT_g = h_bf;
  u16* og = h_bf;
  u16* h2 = q_bf;
  float* x2 = o_f;

  dim3 blk(256);
  dim3 blk2(512);

  // merged weight transposes: one launch
  WTJobs jobs;
  const float* srcs[8] = {wq, wk, wv, wg, wo, wgate, wup, wdown};
  u16* dsts[8] = {wqT, wkT, wvT, wgT, woT, btGU, btGU, wdT};
  int Rs[8] = {2048, 2048, 2048, 2048, 2048, 2048, 2048, 5504};
  int Cs[8] = {1024, 1024, 2048, 2048, 2048, 5504, 5504, 2048};
  int rmuls[8] = {1, 1, 1, 1, 1, 2, 2, 1};
  int roffs[8] = {0, 0, 0, 0, 0, 0, 1, 0};
  int nb = 0;
  for (int j = 0; j < 8; ++j) {
    jobs.src[j] = srcs[j]; jobs.dst[j] = dsts[j];
    jobs.R[j] = Rs[j]; jobs.C[j] = Cs[j];
    jobs.rmul[j] = rmuls[j]; jobs.roff[j] = roffs[j];
    jobs.ntx[j] = Cs[j] / 32;
    jobs.base[j] = nb;
    nb += (Cs[j] / 32) * (Rs[j] / 32);
  }
  wtrans_all<<<nb, blk, 0, stream>>>(jobs);

  rmsnorm_k<<<4096, blk, 0, stream>>>(x, n1w, h_bf);

  // q+k fused (Bt = wqT|wkT contiguous, gemm3 BK=64, 256 blocks)
  gemm3<5, u16><<<256, blk2, 0, stream>>>(h_bf, wqT, q_bf, k_bf, 0.08838834764831845f,
                                          4096, 2048, 2048, 16);
  // v+gate fused (wvT|wgT contiguous, gemm4 BK=64 BN=256, 256 blocks)
  gemm4<4, u16><<<256, blk2, 0, stream>>>(h_bf, wvT, vT_g, gate_bf, 1.f,
                                          4096, 4096, 2048, 16);
  lowrank_k<<<4096, blk, 0, stream>>>(h_bf, gw1, gw2, gb, g_f);

  // h_bf dead from here; reuse as keT panels
  gprep_k<<<512, dim3(128), 0, stream>>>(q_bf, k_bf, g_f, keT_g, ebl_g);

  gla_scan<<<64, blk, 0, stream>>>(q_bf, k_bf, keT_g, vT_g, ebl_g, o_f);

  ogate_k<<<4096, blk, 0, stream>>>(o_f, gate_bf, gnw, og);

  gemm3<1, float><<<256, blk2, 0, stream>>>(og, woT, x2, (void*)x, 1.f,
                                            4096, 2048, 2048, 16);

  rmsnorm_k<<<4096, blk, 0, stream>>>(x2, fnw, h2);

  gemm4<6, u16><<<688, blk2, 0, stream>>>(h2, btGU, mid, nullptr, 1.f,
                                          4096, 11008, 2048, 43);
  gemm3<1, float><<<256, blk2, 0, stream>>>(mid, wdT, out, x2, 1.f,
                                            4096, 2048, 5504, 16);
}

// Round 16
// 921.610 us; speedup vs baseline: 2.1169x; 2.1169x over previous
//
#include <hip/hip_runtime.h>

typedef unsigned short u16;
typedef __attribute__((ext_vector_type(8))) short bh8;   // 8 x bf16 bits (4 VGPRs)
typedef __attribute__((ext_vector_type(4))) float f4;    // MFMA accumulator

__device__ __forceinline__ float bf2f(u16 u) {
  union { unsigned int i; float f; } x; x.i = ((unsigned int)u) << 16; return x.f;
}
__device__ __forceinline__ u16 f2bf(float f) {
  union { float f; unsigned int i; } x; x.f = f;
  unsigned int r = x.i + 0x7fffu + ((x.i >> 16) & 1u);
  return (u16)(r >> 16);
}
__device__ __forceinline__ f4 mfma16(bh8 a, bh8 b, f4 c) {
  return __builtin_amdgcn_mfma_f32_16x16x32_bf16(a, b, c, 0, 0, 0);
}
__device__ __forceinline__ void gload16(const void* g, void* l) {
  __builtin_amdgcn_global_load_lds(
      (const __attribute__((address_space(1))) void*)g,
      (__attribute__((address_space(3))) void*)l, 16, 0, 0);
}

// swizzled LDS read: dense row-major array, byte-in-row XOR'd by (row&7)<<4
__device__ __forceinline__ bh8 rd8(const u16* arr, int row, int col, int rowbytes) {
  return *(const bh8*)((const char*)arr + row * rowbytes + ((col * 2) ^ ((row & 7) << 4)));
}

// ---------------- merged weight transpose: 8 jobs in one launch ----------------
// fp32 [R][C] -> bf16 [C*rmul+roff][R]
struct WTJobs {
  const float* src[8];
  u16* dst[8];
  int R[8], C[8], rmul[8], roff[8], ntx[8], base[8];  // base ascending
};

__global__ __launch_bounds__(256)
void wtrans_all(WTJobs jobs) {
  __shared__ float tile[32][33];
  int bid = blockIdx.x;
  int ji = 0;
#pragma unroll
  for (int k = 1; k < 8; ++k) ji += (bid >= jobs.base[k]);
  int rel = bid - jobs.base[ji];
  int ntx = jobs.ntx[ji];
  int bx = rel % ntx, by = rel / ntx;
  const float* src = jobs.src[ji];
  u16* dst = jobs.dst[ji];
  int R = jobs.R[ji], C = jobs.C[ji], rmul = jobs.rmul[ji], roff = jobs.roff[ji];

  int tx = threadIdx.x & 31, ty = threadIdx.x >> 5;
  int c0 = bx * 32, r0 = by * 32;
#pragma unroll
  for (int yy = 0; yy < 32; yy += 8)
    tile[ty + yy][tx] = src[(size_t)(r0 + ty + yy) * C + c0 + tx];
  __syncthreads();
#pragma unroll
  for (int yy = 0; yy < 32; yy += 8)
    dst[(size_t)((c0 + ty + yy) * rmul + roff) * R + r0 + tx] = f2bf(tile[tx][ty + yy]);
}

// ---------------- RMSNorm over D=2048, fp32 in -> bf16 out ----------------
__global__ __launch_bounds__(256)
void rmsnorm_k(const float* __restrict__ x, const float* __restrict__ w,
               u16* __restrict__ out) {
  int row = blockIdx.x, t = threadIdx.x;
  const float* xr = x + (size_t)row * 2048;
  float4 a = ((const float4*)xr)[t * 2];
  float4 b = ((const float4*)xr)[t * 2 + 1];
  float ss = a.x*a.x + a.y*a.y + a.z*a.z + a.w*a.w
           + b.x*b.x + b.y*b.y + b.z*b.z + b.w*b.w;
#pragma unroll
  for (int s = 32; s > 0; s >>= 1) ss += __shfl_xor(ss, s, 64);
  __shared__ float red[4];
  if ((t & 63) == 0) red[t >> 6] = ss;
  __syncthreads();
  float rr = rsqrtf((red[0] + red[1] + red[2] + red[3]) * (1.0f / 2048.0f) + 1e-6f);
  float v[8] = {a.x, a.y, a.z, a.w, b.x, b.y, b.z, b.w};
  int c0 = t * 8;
  u16* orow = out + (size_t)row * 2048 + c0;
#pragma unroll
  for (int j = 0; j < 8; ++j) orow[j] = f2bf(v[j] * rr * w[c0 + j]);
}

// ======================= gemm2: 512-thread GEMM, BN=256 (R8/R11 K-loop) =======================
// C[M][N] = A[M][K] @ Bt[N][K]^T. BM=256, BN=256, BK=32, 8 waves (2x4),
// wave tile 128x64, acc[8][4]. 3 LDS slots of 32KB. Proven R13/R14 config.
// EPI 4: v panels / gate ; EPI 6: interleaved gate/up -> silu(gate)*up.
template <int EPI, typename OutT>
__global__ __launch_bounds__(512, 2)
void gemm2(const u16* __restrict__ A, const u16* __restrict__ Bt,
           OutT* __restrict__ C, void* __restrict__ aux, float scale,
           int M, int N, int K, int gx) {
  constexpr int SB = 32768;
  __shared__ char lds[3 * SB];
  int t = threadIdx.x, lane = t & 63, w = t >> 6;
  int c_ = lane & 15, r_ = lane >> 4;
  int wm = w >> 2, wn = w & 3;

  int nwg = gridDim.x;
  int wg = (blockIdx.x & 7) * (nwg >> 3) + (blockIdx.x >> 3);
  int gy = nwg / gx;
  int bx = wg / gy, by = wg % gy;
  int m0 = by * 256, n0 = bx * 256;

  const char* baseA[2];
#pragma unroll
  for (int h = 0; h < 2; ++h) {
    int p = h * 512 + t;
    int cc = p ^ ((p >> 3) & 7);
    baseA[h] = (const char*)A + ((size_t)(m0 + (cc >> 2)) * K + (cc & 3) * 8) * 2;
  }
  const char* baseB[2];
#pragma unroll
  for (int h = 0; h < 2; ++h) {
    int p = h * 512 + t;
    int cc = p ^ ((p >> 3) & 7);
    baseB[h] = (const char*)Bt + ((size_t)(n0 + (cc >> 2)) * K + (cc & 3) * 8) * 2;
  }
  int offA[8], offB[4];
#pragma unroll
  for (int mb = 0; mb < 8; ++mb) {
    int cc = (wm * 128 + mb * 16 + c_) * 4 + r_;
    offA[mb] = (cc ^ ((cc >> 3) & 7)) * 16;
  }
#pragma unroll
  for (int nb = 0; nb < 4; ++nb) {
    int cc = (wn * 64 + nb * 16 + c_) * 4 + r_;
    offB[nb] = (cc ^ ((cc >> 3) & 7)) * 16 + 16384;
  }
  int ldsW = w * 1024;

  f4 z4 = {0.f, 0.f, 0.f, 0.f};
  f4 acc[8][4];
#pragma unroll
  for (int mb = 0; mb < 8; ++mb)
#pragma unroll
    for (int nb = 0; nb < 4; ++nb) acc[mb][nb] = z4;

  int NT = K >> 5;

#define STAGEA(S, ko)                                                       \
  {                                                                         \
    _Pragma("unroll") for (int h = 0; h < 2; ++h)                           \
        gload16(baseA[h] + (ko), lds + (S) * SB + h * 8192 + ldsW);         \
  }
#define STAGEB(S, ko)                                                       \
  {                                                                         \
    _Pragma("unroll") for (int h = 0; h < 2; ++h)                           \
        gload16(baseB[h] + (ko), lds + (S) * SB + 16384 + h * 8192 + ldsW); \
  }
#define KTILE(S)                                                            \
  {                                                                         \
    int kts = kt + 2; if (kts >= NT) kts -= NT;                             \
    constexpr int S2 = ((S) + 2) % 3;                                       \
    bh8 fb[4], fa[4];                                                       \
    _Pragma("unroll") for (int nb = 0; nb < 4; ++nb)                        \
        fb[nb] = *(const bh8*)(lds + (S) * SB + offB[nb]);                  \
    _Pragma("unroll") for (int mb = 0; mb < 4; ++mb)                        \
        fa[mb] = *(const bh8*)(lds + (S) * SB + offA[mb]);                  \
    STAGEA(S2, kts << 6);                                                   \
    asm volatile("s_waitcnt lgkmcnt(0)" ::: "memory");                      \
    __builtin_amdgcn_sched_barrier(0);                                      \
    bh8 fa2[4];                                                             \
    _Pragma("unroll") for (int mb = 0; mb < 4; ++mb)                        \
        fa2[mb] = *(const bh8*)(lds + (S) * SB + offA[4 + mb]);             \
    STAGEB(S2, kts << 6);                                                   \
    __builtin_amdgcn_sched_barrier(0);                                      \
    __builtin_amdgcn_s_setprio(1);                                          \
    _Pragma("unroll") for (int mb = 0; mb < 4; ++mb)                        \
        _Pragma("unroll") for (int nb = 0; nb < 4; ++nb)                    \
            acc[mb][nb] = mfma16(fa[mb], fb[nb], acc[mb][nb]);              \
    __builtin_amdgcn_s_setprio(0);                                          \
    asm volatile("s_waitcnt lgkmcnt(0)" ::: "memory");                      \
    __builtin_amdgcn_sched_barrier(0);                                      \
    __builtin_amdgcn_s_setprio(1);                                          \
    _Pragma("unroll") for (int mb = 0; mb < 4; ++mb)                        \
        _Pragma("unroll") for (int nb = 0; nb < 4; ++nb)                    \
            acc[4 + mb][nb] = mfma16(fa2[mb], fb[nb], acc[4 + mb][nb]);     \
    __builtin_amdgcn_s_setprio(0);                                          \
    __builtin_amdgcn_sched_barrier(0);                                      \
    asm volatile("s_waitcnt vmcnt(4)" ::: "memory");                        \
    __builtin_amdgcn_s_barrier();                                           \
    asm volatile("" ::: "memory");                                          \
  }

  STAGEA(0, 0); STAGEB(0, 0);
  STAGEA(1, 64); STAGEB(1, 64);
  asm volatile("s_waitcnt vmcnt(4)" ::: "memory");
  __builtin_amdgcn_s_barrier();
  asm volatile("" ::: "memory");

  int kt = 0;
  while (true) {
    KTILE(0); if (++kt == NT) break;
    KTILE(1); if (++kt == NT) break;
    KTILE(2); if (++kt == NT) break;
  }
  asm volatile("s_waitcnt vmcnt(0)" ::: "memory");
#undef KTILE
#undef STAGEA
#undef STAGEB

  int rowBase = m0 + wm * 128;
#pragma unroll
  for (int mb = 0; mb < 8; ++mb) {
#pragma unroll
    for (int rr = 0; rr < 4; ++rr) {
      int row = rowBase + mb * 16 + r_ * 4 + rr;
#pragma unroll
      for (int nb = 0; nb < 4; ++nb) {
        int col = n0 + wn * 64 + nb * 16 + c_;
        float val = acc[mb][nb][rr];
        if (EPI == 4) {
          if (col < 2048) {
            int bb = row >> 11, t2 = row & 2047;
            int pan = ((bb << 5) + (t2 >> 6)) * 8 + (col >> 8);
            int ii = t2 & 63, vv = col & 255;
            *(u16*)((char*)C + (size_t)pan * 32768 + vv * 128 + ((ii * 2) ^ ((vv & 7) << 4)))
                = f2bf(val);
          } else {
            ((u16*)aux)[(size_t)row * 2048 + col - 2048] = f2bf(val);
          }
        } else if (EPI == 6) {
          float other = __shfl_xor(val, 1, 64);
          if (lane & 1) {
            float gv = other;
            ((u16*)C)[(size_t)row * 5504 + (col >> 1)] = f2bf(val * (gv / (1.f + expf(-gv))));
          }
        }
      }
    }
  }
}

// ======================= gemm3: BK=64 one-barrier GEMM, BN=128 =======================
// BM=256, BN=128, BK=64, 8 waves (4 wm x 2 wn), wave tile 64x64, acc[4][4]
// (~144 regs, no spill). 2 LDS slots of 48KB. Proven R14 config.
// EPI 1: C fp32 = acc + auxF32 ; EPI 5: q/k split.
template <int EPI, typename OutT>
__global__ __launch_bounds__(512, 2)
void gemm3(const u16* __restrict__ A, const u16* __restrict__ Bt,
           OutT* __restrict__ C, void* __restrict__ aux, float scale,
           int M, int N, int K, int gx) {
  constexpr int SB = 49152;  // A 32KB + B 16KB
  __shared__ char lds[2 * SB];
  int t = threadIdx.x, lane = t & 63, w = t >> 6;
  int c_ = lane & 15, r_ = lane >> 4;
  int wm = w >> 1, wn = w & 1;

  int nwg = gridDim.x;
  int wg = (blockIdx.x & 7) * (nwg >> 3) + (blockIdx.x >> 3);
  int gy = nwg / gx;
  int bx = wg / gy, by = wg % gy;
  int m0 = by * 256, n0 = bx * 128;

  int trow = t >> 3;
  int kchunk = (t & 7) ^ (trow & 7);  // pre-swizzled global k-chunk
  const char* baseA[4];
#pragma unroll
  for (int l = 0; l < 4; ++l)
    baseA[l] = (const char*)A + ((size_t)(m0 + l * 64 + trow) * K + kchunk * 8) * 2;
  const char* baseB[2];
#pragma unroll
  for (int l = 0; l < 2; ++l)
    baseB[l] = (const char*)Bt + ((size_t)(n0 + l * 64 + trow) * K + kchunk * 8) * 2;

  int offA[4][2], offB[4][2];
#pragma unroll
  for (int mb = 0; mb < 4; ++mb) {
    int row = wm * 64 + mb * 16 + c_;
#pragma unroll
    for (int ks = 0; ks < 2; ++ks)
      offA[mb][ks] = row * 128 + (((ks * 4 + r_) ^ (row & 7)) << 4);
  }
#pragma unroll
  for (int nb = 0; nb < 4; ++nb) {
    int n = wn * 64 + nb * 16 + c_;
#pragma unroll
    for (int ks = 0; ks < 2; ++ks)
      offB[nb][ks] = 32768 + n * 128 + (((ks * 4 + r_) ^ (n & 7)) << 4);
  }
  int ldsW = w * 1024;

  f4 z4 = {0.f, 0.f, 0.f, 0.f};
  f4 acc[4][4];
#pragma unroll
  for (int mb = 0; mb < 4; ++mb)
#pragma unroll
    for (int nb = 0; nb < 4; ++nb) acc[mb][nb] = z4;

  int NT = K >> 6;  // K=2048 -> 32, K=5504 -> 86

#define STAGE(S, ko)                                                        \
  {                                                                         \
    _Pragma("unroll") for (int l = 0; l < 4; ++l)                           \
        gload16(baseA[l] + (ko), lds + (S) * SB + l * 8192 + ldsW);         \
    _Pragma("unroll") for (int l = 0; l < 2; ++l)                           \
        gload16(baseB[l] + (ko), lds + (S) * SB + 32768 + l * 8192 + ldsW); \
  }
#define KT64(S)                                                             \
  {                                                                         \
    int kts = kt + 1; if (kts >= NT) kts -= NT;                             \
    STAGE((S) ^ 1, kts << 7);                                               \
    _Pragma("unroll")                                                       \
    for (int ks = 0; ks < 2; ++ks) {                                        \
      bh8 fb[4], fa[4];                                                     \
      _Pragma("unroll") for (int nb = 0; nb < 4; ++nb)                      \
          fb[nb] = *(const bh8*)(lds + (S) * SB + offB[nb][ks]);            \
      _Pragma("unroll") for (int mb = 0; mb < 4; ++mb)                      \
          fa[mb] = *(const bh8*)(lds + (S) * SB + offA[mb][ks]);            \
      asm volatile("s_waitcnt lgkmcnt(0)" ::: "memory");                    \
      __builtin_amdgcn_sched_barrier(0);                                    \
      __builtin_amdgcn_s_setprio(1);                                        \
      _Pragma("unroll") for (int mb = 0; mb < 4; ++mb)                      \
          _Pragma("unroll") for (int nb = 0; nb < 4; ++nb)                  \
              acc[mb][nb] = mfma16(fa[mb], fb[nb], acc[mb][nb]);            \
      __builtin_amdgcn_s_setprio(0);                                        \
      __builtin_amdgcn_sched_barrier(0);                                    \
    }                                                                       \
    asm volatile("s_waitcnt vmcnt(0)" ::: "memory");                        \
    __builtin_amdgcn_s_barrier();                                           \
    asm volatile("" ::: "memory");                                          \
  }

  STAGE(0, 0);
  asm volatile("s_waitcnt vmcnt(0)" ::: "memory");
  __builtin_amdgcn_s_barrier();
  asm volatile("" ::: "memory");

  int kt = 0;
  while (true) {
    KT64(0); if (++kt == NT) break;
    KT64(1); if (++kt == NT) break;
  }
#undef KT64
#undef STAGE

  int rowBase = m0 + wm * 64;
#pragma unroll
  for (int mb = 0; mb < 4; ++mb) {
#pragma unroll
    for (int rr = 0; rr < 4; ++rr) {
      int row = rowBase + mb * 16 + r_ * 4 + rr;
#pragma unroll
      for (int nb = 0; nb < 4; ++nb) {
        int col = n0 + wn * 64 + nb * 16 + c_;
        float val = acc[mb][nb][rr];
        if (EPI == 1) {
          ((float*)C)[(size_t)row * N + col] = val + ((const float*)aux)[(size_t)row * N + col];
        } else if (EPI == 5) {
          if (col < 1024) ((u16*)C)[(size_t)row * 1024 + col] = f2bf(val * scale);
          else ((u16*)aux)[(size_t)row * 1024 + col - 1024] = f2bf(val);
        }
      }
    }
  }
}

// ---------------- low-rank gate path: g = log_sigmoid(h@w1@w2 + b)/16 ----------------
__global__ __launch_bounds__(256)
void lowrank_k(const u16* __restrict__ h, const float* __restrict__ w1,
               const float* __restrict__ w2, const float* __restrict__ bias,
               float* __restrict__ g) {
  int row = blockIdx.x, t = threadIdx.x, lane = t & 63, wave = t >> 6;
  const u16* hr = h + (size_t)row * 2048;
  bh8 hv = *(const bh8*)&hr[t * 8];
  float p[16];
#pragma unroll
  for (int j = 0; j < 16; ++j) p[j] = 0.f;
#pragma unroll
  for (int kk = 0; kk < 8; ++kk) {
    float f = bf2f((u16)hv[kk]);
    const float* wrow = w1 + (size_t)(t * 8 + kk) * 16;
#pragma unroll
    for (int j = 0; j < 16; ++j) p[j] += f * wrow[j];
  }
#pragma unroll
  for (int j = 0; j < 16; ++j)
#pragma unroll
    for (int s = 32; s > 0; s >>= 1) p[j] += __shfl_xor(p[j], s, 64);
  __shared__ float gl[4][16];
  if (lane == 0) {
#pragma unroll
    for (int j = 0; j < 16; ++j) gl[wave][j] = p[j];
  }
  __syncthreads();
  float glow[16];
#pragma unroll
  for (int j = 0; j < 16; ++j) glow[j] = gl[0][j] + gl[1][j] + gl[2][j] + gl[3][j];
  float* grow = g + (size_t)row * 1024;
#pragma unroll
  for (int nn = 0; nn < 4; ++nn) {
    int n = nn * 256 + t;
    float z = bias[n];
#pragma unroll
    for (int j = 0; j < 16; ++j) z += glow[j] * w2[j * 1024 + n];
    float ls = fminf(z, 0.f) - log1pf(expf(-fabsf(z)));
    grow[n] = ls * (1.0f / 16.0f);
  }
}

// ---------------- gating prep (parallel over B*nc*H = 512 blocks) ----------------
__global__ __launch_bounds__(128)
void gprep_k(u16* __restrict__ q, u16* __restrict__ k, const float* __restrict__ g,
             u16* __restrict__ keT, float* __restrict__ ebl) {
  int bid = blockIdx.x;            // ((b*32+c)*8+h)
  int h = bid & 7, bc = bid >> 3;
  int b = bc >> 5, c = bc & 31;
  int ch = threadIdx.x;            // 0..127
  size_t base = ((size_t)(b * 2048 + c * 64)) * 1024 + h * 128 + ch;
  char* keTp = (char*)keT + (size_t)bid * 16384 + ch * 128;
  int sw = (ch & 7) << 4;
  float bacc = 0.f;
  for (int i8 = 0; i8 < 8; ++i8) {
    u16 kp[8];
#pragma unroll
    for (int e = 0; e < 8; ++e) {
      size_t off = base + (size_t)(i8 * 8 + e) * 1024;
      bacc += g[off];
      float eb = __expf(bacc);
      float reb = __builtin_amdgcn_rcpf(eb);
      float qv = bf2f(q[off]), kv = bf2f(k[off]);
      q[off] = f2bf(qv * eb);
      u16 kev = f2bf(kv * reb);
      k[off] = kev;
      kp[e] = kev;
    }
    *(bh8*)(keTp + ((i8 * 16) ^ sw)) = *(const bh8*)kp;
  }
  ebl[(size_t)bid * 128 + ch] = __expf(bacc);
}

// ---------------- GLA chunked scan (inter + intra, MFMA only) ----------------
__global__ __launch_bounds__(256)
void gla_scan(const u16* __restrict__ qg, const u16* __restrict__ kg,
              const u16* __restrict__ keTg, const u16* __restrict__ vTg,
              const float* __restrict__ eblg, float* __restrict__ outp) {
  __shared__ u16 qeL[64 * 128];   // [i][ch] swizzled
  __shared__ u16 keL[64 * 128];   // [i][ch] swizzled
  __shared__ u16 kTL[128 * 64];   // [ch][i] swizzled (baked by gprep)
  __shared__ u16 vTL[64 * 64];    // [v][i]  swizzled (baked by V-GEMM)
  __shared__ u16 AL[64 * 64];     // [i][j]  swizzled
  __shared__ u16 SbL[64 * 128];   // S^T bf16 [v][ch] swizzled
  __shared__ float SfL[64][133];  // S^T fp32 master (padded)

  int t = threadIdx.x, lane = t & 63, w = t >> 6;
  int vb = blockIdx.x & 3, bh = blockIdx.x >> 2;
  int b = bh >> 3, h = bh & 7;
  int c_ = lane & 15, r_ = lane >> 4;
  f4 z4 = {0.f, 0.f, 0.f, 0.f};

  for (int i = t; i < 64 * 128; i += 256) SbL[i] = 0;
  for (int i = t; i < 64 * 133; i += 256) ((float*)SfL)[i] = 0.f;

  const char* qbase = (const char*)qg + (size_t)b * 2048 * 2048 + h * 256;
  const char* kbase = (const char*)kg + (size_t)b * 2048 * 2048 + h * 256;
  int rowoff = (t >> 4) * 2048 + (t & 15) * 16;
  int4 pq[4], pk[4], pkt[4], pvt[2];

#define LOADCH(cc)                                                              \
  {                                                                             \
    const char* qc = qbase + (size_t)(cc) * 64 * 2048;                          \
    const char* kc = kbase + (size_t)(cc) * 64 * 2048;                          \
    int panel_ = ((b * 32 + (cc)) * 8 + h);                                     \
    const char* ktc = (const char*)keTg + (size_t)panel_ * 16384;               \
    const char* vtc = (const char*)vTg + (size_t)panel_ * 32768 + vb * 8192;    \
    _Pragma("unroll")                                                           \
    for (int j = 0; j < 4; ++j) {                                               \
      pq[j] = *(const int4*)(qc + j * 16 * 2048 + rowoff);                      \
      pk[j] = *(const int4*)(kc + j * 16 * 2048 + rowoff);                      \
      pkt[j] = *(const int4*)(ktc + j * 4096 + t * 16);                         \
    }                                                                           \
    _Pragma("unroll")                                                           \
    for (int j = 0; j < 2; ++j) pvt[j] = *(const int4*)(vtc + j * 4096 + t * 16); \
  }

  LOADCH(0);
  for (int c = 0; c < 32; ++c) {
#pragma unroll
    for (int j = 0; j < 4; ++j) {
      int L = j * 4096 + t * 16;
      int d = (L & ~255) | ((L & 255) ^ (((L >> 8) & 7) << 4));
      *(int4*)((char*)qeL + d) = pq[j];
      *(int4*)((char*)keL + d) = pk[j];
      *(int4*)((char*)kTL + L) = pkt[j];
    }
#pragma unroll
    for (int j = 0; j < 2; ++j) *(int4*)((char*)vTL + j * 4096 + t * 16) = pvt[j];
    if (c < 31) LOADCH(c + 1);
    int panel = ((b * 32 + c) * 8 + h);
    float eblr[2][4];
#pragma unroll
    for (int kt = 0; kt < 2; ++kt)
#pragma unroll
      for (int r = 0; r < 4; ++r)
        eblr[kt][r] = eblg[(size_t)panel * 128 + w * 32 + kt * 16 + r_ * 4 + r];
    __syncthreads();

    // phase 2: A = tril(qe@ke^T)  and  accS = keT@v
    f4 accA[4] = {z4, z4, z4, z4};
    f4 accS[2][4] = {{z4, z4, z4, z4}, {z4, z4, z4, z4}};
#pragma unroll
    for (int ks = 0; ks < 4; ++ks) {
      bh8 a = rd8(qeL, w * 16 + c_, ks * 32 + r_ * 8, 256);
#pragma unroll
      for (int n = 0; n < 4; ++n)
        accA[n] = mfma16(a, rd8(keL, n * 16 + c_, ks * 32 + r_ * 8, 256), accA[n]);
    }
#pragma unroll
    for (int ks = 0; ks < 2; ++ks) {
      bh8 bf_[4];
#pragma unroll
      for (int n = 0; n < 4; ++n) bf_[n] = rd8(vTL, n * 16 + c_, ks * 32 + r_ * 8, 128);
#pragma unroll
      for (int kt = 0; kt < 2; ++kt) {
        bh8 a = rd8(kTL, w * 32 + kt * 16 + c_, ks * 32 + r_ * 8, 128);
#pragma unroll
        for (int n = 0; n < 4; ++n) accS[kt][n] = mfma16(a, bf_[n], accS[kt][n]);
      }
    }
#pragma unroll
    for (int n = 0; n < 4; ++n)
#pragma unroll
      for (int r = 0; r < 4; ++r) {
        int i = w * 16 + r_ * 4 + r, j = n * 16 + c_;
        *(u16*)((char*)AL + i * 128 + ((j * 2) ^ ((i & 7) << 4))) =
            (j <= i) ? f2bf(accA[n][r]) : (u16)0;
      }
    __syncthreads();

    // phase 3: o = qe@S^T' + A@v
    f4 acco[4] = {z4, z4, z4, z4};
#pragma unroll
    for (int ks = 0; ks < 4; ++ks) {
      bh8 a = rd8(qeL, w * 16 + c_, ks * 32 + r_ * 8, 256);
#pragma unroll
      for (int n = 0; n < 4; ++n)
        acco[n] = mfma16(a, rd8(SbL, n * 16 + c_, ks * 32 + r_ * 8, 256), acco[n]);
    }
#pragma unroll
    for (int ks = 0; ks < 2; ++ks) {
      bh8 a = rd8(AL, w * 16 + c_, ks * 32 + r_ * 8, 128);
#pragma unroll
      for (int n = 0; n < 4; ++n)
        acco[n] = mfma16(a, rd8(vTL, n * 16 + c_, ks * 32 + r_ * 8, 128), acco[n]);
    }
    {
      size_t obase = (size_t)(b * 2048 + c * 64 + w * 16 + r_ * 4) * 2048 + h * 256 + vb * 64;
#pragma unroll
      for (int n = 0; n < 4; ++n)
#pragma unroll
        for (int r = 0; r < 4; ++r)
          outp[obase + (size_t)r * 2048 + n * 16 + c_] = acco[n][r];
    }
    __syncthreads();

    // phase 4: S = ebl * (S + accS)
#pragma unroll
    for (int kt = 0; kt < 2; ++kt)
#pragma unroll
      for (int n = 0; n < 4; ++n)
#pragma unroll
        for (int r = 0; r < 4; ++r) {
          int kk = w * 32 + kt * 16 + r_ * 4 + r;
          int vcol = n * 16 + c_;
          float nv = eblr[kt][r] * (SfL[vcol][kk] + accS[kt][n][r]);
          SfL[vcol][kk] = nv;
          *(u16*)((char*)SbL + vcol * 256 + ((kk * 2) ^ ((vcol & 7) << 4))) = f2bf(nv);
        }
    __syncthreads();
  }
#undef LOADCH
}

// ---------------- per-head RMSNorm * swish(gate) ----------------
__global__ __launch_bounds__(256)
void ogate_k(const float* __restrict__ o, const u16* __restrict__ gate,
             const float* __restrict__ gw, u16* __restrict__ og) {
  int tok = blockIdx.x, t = threadIdx.x;
  int head = t >> 5, l32 = t & 31, v0 = l32 * 8;
  size_t base = (size_t)tok * 2048 + head * 256 + v0;
  float4 a = *(const float4*)&o[base];
  float4 b = *(const float4*)&o[base + 4];
  float ov[8] = {a.x, a.y, a.z, a.w, b.x, b.y, b.z, b.w};
  float ss = 0.f;
#pragma unroll
  for (int j = 0; j < 8; ++j) ss += ov[j] * ov[j];
#pragma unroll
  for (int s = 16; s > 0; s >>= 1) ss += __shfl_xor(ss, s, 32);
  float rr = rsqrtf(ss * (1.0f / 256.0f) + 1e-6f);
#pragma unroll
  for (int j = 0; j < 8; ++j) {
    float gv = bf2f(gate[base + j]);
    float val = ov[j] * rr * gw[v0 + j];
    og[base + j] = f2bf(val * gv / (1.f + expf(-gv)));
  }
}

// ---------------- launch ----------------
extern "C" void kernel_launch(void* const* d_in, const int* in_sizes, int n_in,
                              void* d_out, int out_size, void* d_ws, size_t ws_size,
                              hipStream_t stream) {
  (void)in_sizes; (void)n_in; (void)out_size; (void)ws_size;
  const float* x = (const float*)d_in[0];
  const float* n1w = (const float*)d_in[1];
  const float* wq = (const float*)d_in[2];
  const float* wk = (const float*)d_in[3];
  const float* wv = (const float*)d_in[4];
  const float* gw1 = (const float*)d_in[5];
  const float* gw2 = (const float*)d_in[6];
  const float* gb = (const float*)d_in[7];
  const float* wg = (const float*)d_in[8];
  const float* gnw = (const float*)d_in[9];
  const float* wo = (const float*)d_in[10];
  const float* fnw = (const float*)d_in[11];
  const float* wgate = (const float*)d_in[12];
  const float* wup = (const float*)d_in[13];
  const float* wdown = (const float*)d_in[14];
  float* out = (float*)d_out;

  char* ws = (char*)d_ws;
  size_t off = 0;
  auto alloc = [&](size_t bytes) { size_t p = off; off += (bytes + 255) & ~(size_t)255; return p; };
  u16* wqT = (u16*)(ws + alloc(2ull * 1024 * 2048));   // [contiguous with wkT -> qk Bt]
  u16* wkT = (u16*)(ws + alloc(2ull * 1024 * 2048));
  u16* wvT = (u16*)(ws + alloc(2ull * 2048 * 2048));   // [contiguous with wgT -> vg Bt]
  u16* wgT = (u16*)(ws + alloc(2ull * 2048 * 2048));
  u16* woT = (u16*)(ws + alloc(2ull * 2048 * 2048));
  u16* btGU = (u16*)(ws + alloc(2ull * 11008 * 2048)); // interleaved gate/up
  u16* wdT = (u16*)(ws + alloc(2ull * 2048 * 5504));
  u16* h_bf = (u16*)(ws + alloc(2ull * 4096 * 2048));  // h -> keT panels -> og
  u16* q_bf = (u16*)(ws + alloc(2ull * 4096 * 1024));  // q -> qe (in place) -> h2
  u16* k_bf = (u16*)(ws + alloc(2ull * 4096 * 1024));  // k -> ke (in place)
  u16* vT_g = (u16*)(ws + alloc(2ull * 4096 * 2048));  // v panels [512][256][64] swizzled
  u16* gate_bf = (u16*)(ws + alloc(2ull * 4096 * 2048));
  float* g_f = (float*)(ws + alloc(4ull * 4096 * 1024));
  float* o_f = (float*)(ws + alloc(4ull * 4096 * 2048));  // later reused as x2
  u16* mid = (u16*)(ws + alloc(2ull * 4096 * 5504));
  float* ebl_g = (float*)(ws + alloc(4ull * 512 * 128));
  u16* keT_g = h_bf;
  u16* og = h_bf;
  u16* h2 = q_bf;
  float* x2 = o_f;

  dim3 blk(256);
  dim3 blk2(512);

  // merged weight transposes: one launch
  WTJobs jobs;
  const float* srcs[8] = {wq, wk, wv, wg, wo, wgate, wup, wdown};
  u16* dsts[8] = {wqT, wkT, wvT, wgT, woT, btGU, btGU, wdT};
  int Rs[8] = {2048, 2048, 2048, 2048, 2048, 2048, 2048, 5504};
  int Cs[8] = {1024, 1024, 2048, 2048, 2048, 5504, 5504, 2048};
  int rmuls[8] = {1, 1, 1, 1, 1, 2, 2, 1};
  int roffs[8] = {0, 0, 0, 0, 0, 0, 1, 0};
  int nb = 0;
  for (int j = 0; j < 8; ++j) {
    jobs.src[j] = srcs[j]; jobs.dst[j] = dsts[j];
    jobs.R[j] = Rs[j]; jobs.C[j] = Cs[j];
    jobs.rmul[j] = rmuls[j]; jobs.roff[j] = roffs[j];
    jobs.ntx[j] = Cs[j] / 32;
    jobs.base[j] = nb;
    nb += (Cs[j] / 32) * (Rs[j] / 32);
  }
  wtrans_all<<<nb, blk, 0, stream>>>(jobs);

  rmsnorm_k<<<4096, blk, 0, stream>>>(x, n1w, h_bf);

  // q+k fused (Bt = wqT|wkT contiguous, gemm3 BK=64, 256 blocks)
  gemm3<5, u16><<<256, blk2, 0, stream>>>(h_bf, wqT, q_bf, k_bf, 0.08838834764831845f,
                                          4096, 2048, 2048, 16);
  // v+gate fused (wvT|wgT contiguous, gemm2 BN=256 -> 256 blocks)
  gemm2<4, u16><<<256, blk2, 0, stream>>>(h_bf, wvT, vT_g, gate_bf, 1.f,
                                          4096, 4096, 2048, 16);
  lowrank_k<<<4096, blk, 0, stream>>>(h_bf, gw1, gw2, gb, g_f);

  // h_bf dead from here; reuse as keT panels
  gprep_k<<<512, dim3(128), 0, stream>>>(q_bf, k_bf, g_f, keT_g, ebl_g);

  gla_scan<<<64, blk, 0, stream>>>(q_bf, k_bf, keT_g, vT_g, ebl_g, o_f);

  ogate_k<<<4096, blk, 0, stream>>>(o_f, gate_bf, gnw, og);

  gemm3<1, float><<<256, blk2, 0, stream>>>(og, woT, x2, (void*)x, 1.f,
                                            4096, 2048, 2048, 16);

  rmsnorm_k<<<4096, blk, 0, stream>>>(x2, fnw, h2);

  gemm2<6, u16><<<688, blk2, 0, stream>>>(h2, btGU, mid, nullptr, 1.f,
                                          4096, 11008, 2048, 43);
  gemm3<1, float><<<256, blk2, 0, stream>>>(mid, wdT, out, x2, 1.f,
                                            4096, 2048, 5504, 16);
}